// Round 4
// baseline (18014.545 us; speedup 1.0000x reference)
//
#include <hip/hip_runtime.h>
#include <math.h>

#define NN 2000
#define BB 32
#define TT 24
#define T_OUT 12
#define HH 64
#define DD 10
#define NP 2048   // padded node dim
#define BC 2048   // B*H columns (j = b*64 + c)

typedef unsigned short ushort_t;
typedef __bf16 bf16x8 __attribute__((ext_vector_type(8)));
typedef float f32x4 __attribute__((ext_vector_type(4)));

__device__ __forceinline__ float sigmoidf_(float x) { return 1.f / (1.f + expf(-x)); }

__device__ __forceinline__ ushort_t f2bf(float f) {
    unsigned int u = __float_as_uint(f);
    unsigned int r = (u + 0x7FFFu + ((u >> 16) & 1u)) >> 16;
    return (ushort_t)r;
}
__device__ __forceinline__ float bf2f(ushort_t s) {
    return __uint_as_float(((unsigned int)s) << 16);
}

// ---------------- workspace layout (bytes) ----------------
constexpr size_t SZ_NPNP2 = (size_t)NP * NP * 2;      // 8,388,608
constexpr size_t SZ_ST4   = (size_t)NN * BC * 4;      // 16,384,000
constexpr size_t SZ_ST2   = (size_t)NN * BC * 2;      // 8,192,000

// base region (both paths) — top = 129,613,824 B (round-2-proven envelope)
constexpr size_t ABF_OFF  = 0;
constexpr size_t H1T_OFF  = ABF_OFF + SZ_NPNP2;
constexpr size_t TMPT_OFF = H1T_OFF + SZ_NPNP2;
constexpr size_t H0F_OFF  = TMPT_OFF + SZ_NPNP2;
constexpr size_t H1F_OFF  = H0F_OFF + SZ_ST4;
constexpr size_t ZF_OFF   = H1F_OFF + SZ_ST4;         // f32; overlaid with A_f32 in setup
constexpr size_t H0B_OFF  = ZF_OFF + SZ_ST4;
constexpr size_t H1B_OFF  = H0B_OFF + SZ_ST2;
constexpr size_t RHB_OFF  = H1B_OFF + SZ_ST2;
constexpr size_t AH0_OFF  = RHB_OFF + SZ_ST2;
constexpr size_t AH1_OFF  = AH0_OFF + SZ_ST2;
constexpr size_t ARH_OFF  = AH1_OFF + SZ_ST2;
constexpr size_t AXF_OFF  = ARH_OFF + SZ_ST2;         // [B][T][N] f32: 6,144,000
constexpr size_t BASE_TOP = AXF_OFF + (size_t)BB * TT * NN * 4;

// Path-A extension (materialized per-node weights)
constexpr size_t WG0_OFF  = BASE_TOP;
constexpr size_t WXG0_OFF = WG0_OFF + (size_t)NN * 128 * 128 * 2;   // 65,536,000
constexpr size_t WC0_OFF  = WXG0_OFF + (size_t)NN * 128 * 2 * 2;    // 1,024,000
constexpr size_t WXC0_OFF = WC0_OFF + (size_t)NN * 64 * 128 * 2;    // 32,768,000
constexpr size_t WG1_OFF  = WXC0_OFF + (size_t)NN * 64 * 2 * 2;     // 512,000
constexpr size_t WC1_OFF  = WG1_OFF + (size_t)NN * 128 * 256 * 2;   // 131,072,000
constexpr size_t BG0_OFF  = WC1_OFF + (size_t)NN * 64 * 256 * 2;    // 65,536,000
constexpr size_t BC0_OFF  = BG0_OFF + (size_t)NN * 128 * 4;
constexpr size_t BG1_OFF  = BC0_OFF + (size_t)NN * 64 * 4;
constexpr size_t BC1_OFF  = BG1_OFF + (size_t)NN * 128 * 4;
constexpr size_t TOP_A    = BC1_OFF + (size_t)NN * 64 * 4;          // 429,133,824

// ---------------- A_f32 = row_softmax(relu(E E^T)) ----------------
__global__ __launch_bounds__(256) void compute_A_kernel(const float* __restrict__ E,
                                                        float* __restrict__ A) {
    const int row = blockIdx.x;
    const int tid = threadIdx.x;
    float er[DD];
#pragma unroll
    for (int d = 0; d < DD; ++d) er[d] = E[row * DD + d];
    __shared__ float red[8];

    float lmax = -1e30f;
    for (int c = tid; c < NN; c += 256) {
        float s = 0.f;
#pragma unroll
        for (int d = 0; d < DD; ++d) s += er[d] * E[c * DD + d];
        s = fmaxf(s, 0.f);
        A[(size_t)row * NN + c] = s;
        lmax = fmaxf(lmax, s);
    }
#pragma unroll
    for (int o = 32; o > 0; o >>= 1) lmax = fmaxf(lmax, __shfl_down(lmax, o, 64));
    if ((tid & 63) == 0) red[tid >> 6] = lmax;
    __syncthreads();
    const float rmax = fmaxf(fmaxf(red[0], red[1]), fmaxf(red[2], red[3]));
    __syncthreads();

    float lsum = 0.f;
    for (int c = tid; c < NN; c += 256) {
        float v = expf(A[(size_t)row * NN + c] - rmax);
        A[(size_t)row * NN + c] = v;
        lsum += v;
    }
#pragma unroll
    for (int o = 32; o > 0; o >>= 1) lsum += __shfl_down(lsum, o, 64);
    if ((tid & 63) == 0) red[4 + (tid >> 6)] = lsum;
    __syncthreads();
    const float inv = 1.f / (red[4] + red[5] + red[6] + red[7]);
    for (int c = tid; c < NN; c += 256) A[(size_t)row * NN + c] *= inv;
}

// ---------------- A_f32 -> A_bf [2048][2048] with zero pad ----------------
__global__ __launch_bounds__(256) void convert_A(const float* __restrict__ Af,
                                                 ushort_t* __restrict__ Ab) {
    size_t idx = (size_t)blockIdx.x * 256 + threadIdx.x;
    int r = (int)(idx >> 11), c = (int)(idx & 2047);
    float v = (r < NN && c < NN) ? Af[(size_t)r * NN + c] : 0.f;
    Ab[idx] = f2bf(v);
}

// ---------------- Ax[b,t,n] = sum_m A[n,m] x[b,t,m]  (f32, one-time) ----------------
__global__ __launch_bounds__(256) void ax_kernel(const float* __restrict__ A,
                                                 const float* __restrict__ x,
                                                 float* __restrict__ Ax) {
    __shared__ float As[64][65];
    __shared__ float xs[64][25];
    const int n0 = blockIdx.x * 64;
    const int b = blockIdx.y;
    const int tid = threadIdx.x;
    float acc[6] = {0, 0, 0, 0, 0, 0};
    for (int m0 = 0; m0 < NN; m0 += 64) {
#pragma unroll
        for (int l = 0; l < 16; ++l) {
            int idx = tid + l * 256;
            int r = idx >> 6, c = idx & 63;
            int n = n0 + r, m = m0 + c;
            As[r][c] = (n < NN && m < NN) ? A[(size_t)n * NN + m] : 0.f;
        }
        for (int idx = tid; idx < 64 * TT; idx += 256) {
            int c = idx >> 6, r = idx & 63;
            int m = m0 + r;
            xs[r][c] = (m < NN) ? x[((size_t)b * TT + c) * NN + m] : 0.f;
        }
        __syncthreads();
#pragma unroll 4
        for (int mm = 0; mm < 64; ++mm) {
#pragma unroll
            for (int j = 0; j < 6; ++j) {
                int oi = tid + j * 256;
                int r = oi / TT, c = oi % TT;
                acc[j] += As[r][mm] * xs[mm][c];
            }
        }
        __syncthreads();
    }
#pragma unroll
    for (int j = 0; j < 6; ++j) {
        int oi = tid + j * 256;
        int r = oi / TT, c = oi % TT;
        int n = n0 + r;
        if (n < NN) Ax[((size_t)b * TT + c) * NN + n] = acc[j];
    }
}

// ---------------- transpose [n][j] -> [j][n] bf16, zero-fill n>=NN ----------------
template <bool SRC_F32>
__global__ __launch_bounds__(256) void transpose_to_bf(const void* __restrict__ src,
                                                       ushort_t* __restrict__ dst) {
    __shared__ float tile[64][65];
    const int jb = blockIdx.x * 64, nb = blockIdx.y * 64;
    const int tid = threadIdx.x;
#pragma unroll
    for (int l = 0; l < 16; ++l) {
        int idx = tid + l * 256;
        int r = idx >> 6, c = idx & 63;  // r: n-local, c: j-local
        int n = nb + r;
        float v = 0.f;
        if (n < NN)
            v = SRC_F32 ? ((const float*)src)[(size_t)n * BC + jb + c]
                        : bf2f(((const ushort_t*)src)[(size_t)n * BC + jb + c]);
        tile[r][c] = v;
    }
    __syncthreads();
#pragma unroll
    for (int l = 0; l < 16; ++l) {
        int idx = tid + l * 256;
        int r = idx >> 6, c = idx & 63;  // r: j-local, c: n-local
        dst[(size_t)(jb + r) * NP + nb + c] = f2bf(tile[c][r]);
    }
}

// ---------------- MFMA GEMM: Y[n][j] = sum_m A[n][m] * XT[j][m], bf16 ----------------
__global__ __launch_bounds__(256) void gemm_mfma(const ushort_t* __restrict__ Ab,
                                                 const ushort_t* __restrict__ XT,
                                                 ushort_t* __restrict__ Y) {
    __shared__ ushort_t As[128 * 32];
    __shared__ ushort_t Bs[128 * 32];
    const int tid = threadIdx.x;
    const int w = tid >> 6, l = tid & 63;
    const int n0 = blockIdx.x * 128, j0 = blockIdx.y * 128;
    const int wm = w & 1, wj = w >> 1;
    const int lr = l & 15, lg = l >> 4;
    f32x4 acc[4][4] = {};

    const char* Abase = (const char*)Ab;
    const char* Bbase = (const char*)XT;

    for (int ks = 0; ks < NP / 32; ++ks) {
        const int k0 = ks * 32;
#pragma unroll
        for (int p = 0; p < 2; ++p) {
            const int o = p * 4096 + w * 1024 + l * 16;
            const int row = o >> 6, colb = o & 63;
            __builtin_amdgcn_global_load_lds(
                (const __attribute__((address_space(1))) char*)(Abase + (size_t)(n0 + row) * (NP * 2) + k0 * 2 + colb),
                (__attribute__((address_space(3))) char*)((char*)As + o), 16, 0, 0);
            __builtin_amdgcn_global_load_lds(
                (const __attribute__((address_space(1))) char*)(Bbase + (size_t)(j0 + row) * (NP * 2) + k0 * 2 + colb),
                (__attribute__((address_space(3))) char*)((char*)Bs + o), 16, 0, 0);
        }
        __syncthreads();

        bf16x8 af[4], bfv[4];
#pragma unroll
        for (int mt = 0; mt < 4; ++mt)
            af[mt] = *(const bf16x8*)&As[(wm * 64 + mt * 16 + lr) * 32 + lg * 8];
#pragma unroll
        for (int nt = 0; nt < 4; ++nt)
            bfv[nt] = *(const bf16x8*)&Bs[(wj * 64 + nt * 16 + lr) * 32 + lg * 8];
#pragma unroll
        for (int mt = 0; mt < 4; ++mt)
#pragma unroll
            for (int nt = 0; nt < 4; ++nt)
                acc[mt][nt] = __builtin_amdgcn_mfma_f32_16x16x32_bf16(af[mt], bfv[nt], acc[mt][nt], 0, 0, 0);
        __syncthreads();
    }

#pragma unroll
    for (int mt = 0; mt < 4; ++mt) {
#pragma unroll
        for (int r = 0; r < 4; ++r) {
            const int n = n0 + wm * 64 + mt * 16 + lg * 4 + r;
            if (n < NN) {
#pragma unroll
                for (int nt = 0; nt < 4; ++nt) {
                    const int j = j0 + wj * 64 + nt * 16 + lr;
                    Y[(size_t)n * BC + j] = f2bf(acc[mt][nt][r]);
                }
            }
        }
    }
}

// ================= Path A: materialized per-node weights =================
// L0: K=128, k -> (kk=k>>6, i=1+(k&63)); Wx[n][o][{0,1}] = (kk,i=0).
// L1: K=256, k -> (kk=s&1, i=(s>>1)*64+(k&63)), s=k>>6.
template <int CI, int CO, bool L0>
__global__ __launch_bounds__(256) void matW(const float* __restrict__ emb,
                                            const float* __restrict__ Wp,
                                            const float* __restrict__ bp,
                                            ushort_t* __restrict__ Wm,
                                            ushort_t* __restrict__ Wx,
                                            float* __restrict__ bm) {
    constexpr int K = L0 ? 128 : 256;
    const int n = blockIdx.x;
    float e[DD];
#pragma unroll
    for (int d = 0; d < DD; ++d) e[d] = emb[n * DD + d];
    for (int f = threadIdx.x; f < CO * K; f += 256) {
        const int o = f / K;
        const int k = f & (K - 1);
        const int s = k >> 6, c = k & 63;
        const int kk = L0 ? s : (s & 1);
        const int i = L0 ? (1 + c) : ((s >> 1) * 64 + c);
        float a = 0.f;
#pragma unroll
        for (int d = 0; d < DD; ++d)
            a += e[d] * Wp[((size_t)(d * 2 + kk) * CI + i) * CO + o];
        Wm[(size_t)n * CO * K + f] = f2bf(a);
    }
    if (L0) {
        if ((int)threadIdx.x < CO * 2) {
            const int o = threadIdx.x >> 1, kk = threadIdx.x & 1;
            float a = 0.f;
#pragma unroll
            for (int d = 0; d < DD; ++d)
                a += e[d] * Wp[((size_t)(d * 2 + kk) * CI) * CO + o];
            Wx[(size_t)n * CO * 2 + threadIdx.x] = f2bf(a);
        }
    }
    if ((int)threadIdx.x < CO) {
        float a = 0.f;
#pragma unroll
        for (int d = 0; d < DD; ++d) a += e[d] * bp[d * CO + threadIdx.x];
        bm[(size_t)n * CO + threadIdx.x] = a;
    }
}

template <int NSEG, int NW, bool GATE, bool HASX>
__global__ __launch_bounds__(NW * 64) void napl_mfma(
    const ushort_t* __restrict__ Wm, const ushort_t* __restrict__ Wx,
    const float* __restrict__ bm,
    const ushort_t* __restrict__ s0p, const ushort_t* __restrict__ s1p,
    const ushort_t* __restrict__ s2p, const ushort_t* __restrict__ s3p,
    const float* __restrict__ xv, const float* __restrict__ axv,
    const float* __restrict__ hf, float* __restrict__ zf,
    ushort_t* __restrict__ outb, float* __restrict__ outf, int t) {
    constexpr int K = NSEG * 64;
    constexpr int CO = NW * 32;
    const int n = blockIdx.x;
    const int tid = threadIdx.x;
    const int w = tid >> 6, l = tid & 63;
    const int lr = l & 15, lg = l >> 4;
    const int ob = w * 32;
    const size_t nb = (size_t)n * BC;
    const ushort_t* segs[4] = {s0p, s1p, s2p, s3p};
    const ushort_t* wb = Wm + (size_t)n * CO * K;
    f32x4 acc[2][2] = {};

#pragma unroll
    for (int s = 0; s < NSEG; ++s) {
        const ushort_t* sp = segs[s] + nb;
#pragma unroll
        for (int hh = 0; hh < 2; ++hh) {
            const int kin = hh * 32 + lg * 8;
            const int kw = s * 64 + kin;
            bf16x8 af0 = *(const bf16x8*)&sp[lr * 64 + kin];
            bf16x8 af1 = *(const bf16x8*)&sp[(16 + lr) * 64 + kin];
            bf16x8 b0 = *(const bf16x8*)&wb[(size_t)(ob + lr) * K + kw];
            bf16x8 b1 = *(const bf16x8*)&wb[(size_t)(ob + 16 + lr) * K + kw];
            acc[0][0] = __builtin_amdgcn_mfma_f32_16x16x32_bf16(af0, b0, acc[0][0], 0, 0, 0);
            acc[0][1] = __builtin_amdgcn_mfma_f32_16x16x32_bf16(af0, b1, acc[0][1], 0, 0, 0);
            acc[1][0] = __builtin_amdgcn_mfma_f32_16x16x32_bf16(af1, b0, acc[1][0], 0, 0, 0);
            acc[1][1] = __builtin_amdgcn_mfma_f32_16x16x32_bf16(af1, b1, acc[1][1], 0, 0, 0);
        }
    }

    if (HASX) {
        float wx0[2], wx1[2];
#pragma unroll
        for (int nt = 0; nt < 2; ++nt) {
            const ushort_t* p = &Wx[((size_t)n * CO + ob + nt * 16 + lr) * 2];
            wx0[nt] = bf2f(p[0]);
            wx1[nt] = bf2f(p[1]);
        }
#pragma unroll
        for (int mt = 0; mt < 2; ++mt) {
#pragma unroll
            for (int r = 0; r < 4; ++r) {
                const int b = mt * 16 + lg * 4 + r;
                const float xb = xv[((size_t)b * TT + t) * NN + n];
                const float axb = axv[((size_t)b * TT + t) * NN + n];
#pragma unroll
                for (int nt = 0; nt < 2; ++nt)
                    acc[mt][nt][r] += xb * wx0[nt] + axb * wx1[nt];
            }
        }
    }

#pragma unroll
    for (int mt = 0; mt < 2; ++mt) {
#pragma unroll
        for (int r = 0; r < 4; ++r) {
            const int b = mt * 16 + lg * 4 + r;
#pragma unroll
            for (int nt = 0; nt < 2; ++nt) {
                const int o = ob + nt * 16 + lr;
                float val = acc[mt][nt][r] + bm[(size_t)n * CO + o];
                if (GATE) {
                    const float sg = sigmoidf_(val);
                    if (o < 64) {
                        zf[nb + b * 64 + o] = sg;
                    } else {
                        const int oc = o - 64;
                        outb[nb + b * 64 + oc] = f2bf(sg * hf[nb + b * 64 + oc]);
                    }
                } else {
                    const float hc = tanhf(val);
                    const float z = zf[nb + b * 64 + o];
                    const float hn = z * hf[nb + b * 64 + o] + (1.f - z) * hc;
                    outf[nb + b * 64 + o] = hn;
                    outb[nb + b * 64 + o] = f2bf(hn);
                }
            }
        }
    }
}

// ================= Path B: round-2 LDS-rebuild NAPL =================
template <int C1, bool XS, bool GATE>
__global__ __launch_bounds__(256) void napl_kernel(
    const float* __restrict__ emb, const float* __restrict__ Wp,
    const float* __restrict__ bp,
    const float* __restrict__ in1,   // x (XS) or h0f
    const void* __restrict__ in1A_,  // Ax f32 (XS) or Ah0 bf16
    const void* __restrict__ in2_,   // GATE: h f32 ; CAND: rh bf16
    const ushort_t* __restrict__ in2A,
    float* __restrict__ zf,
    void* __restrict__ out2_,        // GATE: rh bf16 out ; CAND: h f32 state
    int t) {
    constexpr int CI = C1 + HH;
    constexpr int CO = GATE ? 2 * HH : HH;
    const int n = blockIdx.x;
    const int part = GATE ? blockIdx.y : 0;
    const int tid = threadIdx.x;

    __shared__ float Wl[2][CI][64];
    __shared__ float bl[64];
    __shared__ float es[DD];
    if (tid < DD) es[tid] = emb[n * DD + tid];
    __syncthreads();

    for (int idx = tid; idx < 2 * CI * 64; idx += 256) {
        int k = idx / (CI * 64);
        int rem = idx - k * CI * 64;
        int i = rem >> 6;
        int o = rem & 63;
        float s = 0.f;
#pragma unroll
        for (int d = 0; d < DD; ++d)
            s += es[d] * Wp[((size_t)(d * 2 + k) * CI + i) * CO + part * 64 + o];
        Wl[k][i][o] = s;
    }
    if (tid < 64) {
        float s = 0.f;
#pragma unroll
        for (int d = 0; d < DD; ++d) s += es[d] * bp[d * CO + part * 64 + tid];
        bl[tid] = s;
    }
    __syncthreads();

    const int oq = tid & 15;
    const int bb = tid >> 4;
    float acc[2][4];
#pragma unroll
    for (int u = 0; u < 2; ++u)
#pragma unroll
        for (int j = 0; j < 4; ++j) acc[u][j] = 0.f;

#pragma unroll 1
    for (int i = 0; i < C1; ++i) {
        float4 w0 = *(const float4*)&Wl[0][i][oq * 4];
        float4 w1 = *(const float4*)&Wl[1][i][oq * 4];
#pragma unroll
        for (int u = 0; u < 2; ++u) {
            const int b = bb + u * 16;
            float v, va;
            if (XS) {
                size_t ix = ((size_t)b * TT + t) * NN + n;
                v = in1[ix];
                va = ((const float*)in1A_)[ix];
            } else {
                size_t ix = (size_t)n * BC + b * 64 + i;
                v = in1[ix];
                va = bf2f(((const ushort_t*)in1A_)[ix]);
            }
            acc[u][0] += v * w0.x + va * w1.x;
            acc[u][1] += v * w0.y + va * w1.y;
            acc[u][2] += v * w0.z + va * w1.z;
            acc[u][3] += v * w0.w + va * w1.w;
        }
    }
#pragma unroll 2
    for (int i2 = 0; i2 < HH; ++i2) {
        const int i = C1 + i2;
        float4 w0 = *(const float4*)&Wl[0][i][oq * 4];
        float4 w1 = *(const float4*)&Wl[1][i][oq * 4];
#pragma unroll
        for (int u = 0; u < 2; ++u) {
            const int b = bb + u * 16;
            size_t ix = (size_t)n * BC + b * 64 + i2;
            float v = GATE ? ((const float*)in2_)[ix] : bf2f(((const ushort_t*)in2_)[ix]);
            float va = bf2f(in2A[ix]);
            acc[u][0] += v * w0.x + va * w1.x;
            acc[u][1] += v * w0.y + va * w1.y;
            acc[u][2] += v * w0.z + va * w1.z;
            acc[u][3] += v * w0.w + va * w1.w;
        }
    }

#pragma unroll
    for (int u = 0; u < 2; ++u) {
        const int b = bb + u * 16;
        const size_t base = (size_t)n * BC + b * 64 + oq * 4;
#pragma unroll
        for (int j = 0; j < 4; ++j) {
            float val = acc[u][j] + bl[oq * 4 + j];
            if (GATE) {
                float s = sigmoidf_(val);
                if (part == 0) {
                    zf[base + j] = s;
                } else {
                    float h = ((const float*)in2_)[base + j];
                    ((ushort_t*)out2_)[base + j] = f2bf(s * h);
                }
            } else {
                float hc = tanhf(val);
                float z = zf[base + j];
                float* hs = (float*)out2_;
                float hp = hs[base + j];
                hs[base + j] = z * hp + (1.f - z) * hc;
            }
        }
    }
}

// ---------------- head: y[b,ot,n] = hb[ot] + sum_h h1[n][b*64+h]*hw[ot,h] ----------------
__global__ __launch_bounds__(256) void head_kernel(const float* __restrict__ h1,
                                                   const float* __restrict__ hw,
                                                   const float* __restrict__ hb,
                                                   float* __restrict__ y) {
    __shared__ float wl[T_OUT * HH];
    const int tid = threadIdx.x;
    for (int idx = tid; idx < T_OUT * HH; idx += 256) wl[idx] = hw[idx];
    __syncthreads();
    const int gi = blockIdx.x * 256 + tid;
    if (gi >= BB * NN) return;
    const int b = gi / NN, n = gi % NN;
    float acc[T_OUT];
#pragma unroll
    for (int ot = 0; ot < T_OUT; ++ot) acc[ot] = hb[ot];
    for (int h = 0; h < HH; ++h) {
        float v = h1[(size_t)n * BC + b * 64 + h];
#pragma unroll
        for (int ot = 0; ot < T_OUT; ++ot) acc[ot] += v * wl[ot * HH + h];
    }
#pragma unroll
    for (int ot = 0; ot < T_OUT; ++ot)
        y[((size_t)b * T_OUT + ot) * NN + n] = acc[ot];
}

extern "C" void kernel_launch(void* const* d_in, const int* in_sizes, int n_in,
                              void* d_out, int out_size, void* d_ws, size_t ws_size,
                              hipStream_t stream) {
    const float* x = (const float*)d_in[0];
    const float* node_emb = (const float*)d_in[1];
    const float* adapt_emb = (const float*)d_in[2];
    const float* Wg0 = (const float*)d_in[3];
    const float* bg0 = (const float*)d_in[4];
    const float* Wc0 = (const float*)d_in[5];
    const float* bc0 = (const float*)d_in[6];
    const float* Wg1 = (const float*)d_in[7];
    const float* bg1 = (const float*)d_in[8];
    const float* Wc1 = (const float*)d_in[9];
    const float* bc1 = (const float*)d_in[10];
    const float* head_w = (const float*)d_in[11];
    const float* head_b = (const float*)d_in[12];
    float* y = (float*)d_out;

    char* ws = (char*)d_ws;
    ushort_t* Abf  = (ushort_t*)(ws + ABF_OFF);
    ushort_t* h1T  = (ushort_t*)(ws + H1T_OFF);
    ushort_t* tmpT = (ushort_t*)(ws + TMPT_OFF);
    float* h0f = (float*)(ws + H0F_OFF);
    float* h1f = (float*)(ws + H1F_OFF);
    float* zf  = (float*)(ws + ZF_OFF);
    ushort_t* h0b = (ushort_t*)(ws + H0B_OFF);
    ushort_t* h1b = (ushort_t*)(ws + H1B_OFF);
    ushort_t* rhb = (ushort_t*)(ws + RHB_OFF);
    ushort_t* Ah0 = (ushort_t*)(ws + AH0_OFF);
    ushort_t* Ah1 = (ushort_t*)(ws + AH1_OFF);
    ushort_t* Arh = (ushort_t*)(ws + ARH_OFF);
    float* Axf = (float*)(ws + AXF_OFF);
    float* Af32 = zf;  // overlay: consumed before first gate writes z

    const bool bigws = (ws_size >= TOP_A);

    hipMemsetAsync(h0f, 0, SZ_ST4, stream);
    hipMemsetAsync(h1f, 0, SZ_ST4, stream);
    hipMemsetAsync(h0b, 0, SZ_ST2, stream);
    hipMemsetAsync(h1b, 0, SZ_ST2, stream);
    hipMemsetAsync(Ah0, 0, SZ_ST2, stream);
    hipMemsetAsync(h1T, 0, SZ_NPNP2, stream);

    compute_A_kernel<<<NN, 256, 0, stream>>>(adapt_emb, Af32);
    ax_kernel<<<dim3((NN + 63) / 64, BB), 256, 0, stream>>>(Af32, x, Axf);
    convert_A<<<(NP * NP) / 256, 256, 0, stream>>>(Af32, Abf);

    const dim3 gG(NP / 128, NP / 128);  // 16 x 16
    const dim3 gT(NP / 64, NP / 64);    // 32 x 32

    if (bigws) {
        // ---------- Path A: materialized weights ----------
        ushort_t* Wg0m = (ushort_t*)(ws + WG0_OFF);
        ushort_t* Wxg0 = (ushort_t*)(ws + WXG0_OFF);
        ushort_t* Wc0m = (ushort_t*)(ws + WC0_OFF);
        ushort_t* Wxc0 = (ushort_t*)(ws + WXC0_OFF);
        ushort_t* Wg1m = (ushort_t*)(ws + WG1_OFF);
        ushort_t* Wc1m = (ushort_t*)(ws + WC1_OFF);
        float* bg0m = (float*)(ws + BG0_OFF);
        float* bc0m = (float*)(ws + BC0_OFF);
        float* bg1m = (float*)(ws + BG1_OFF);
        float* bc1m = (float*)(ws + BC1_OFF);

        matW<65, 128, true><<<NN, 256, 0, stream>>>(node_emb, Wg0, bg0, Wg0m, Wxg0, bg0m);
        matW<65, 64, true><<<NN, 256, 0, stream>>>(node_emb, Wc0, bc0, Wc0m, Wxc0, bc0m);
        matW<128, 128, false><<<NN, 256, 0, stream>>>(node_emb, Wg1, bg1, Wg1m, nullptr, bg1m);
        matW<128, 64, false><<<NN, 256, 0, stream>>>(node_emb, Wc1, bc1, Wc1m, nullptr, bc1m);

        for (int t = 0; t < TT; ++t) {
            gemm_mfma<<<gG, 256, 0, stream>>>(Abf, h1T, Ah1);
            napl_mfma<2, 4, true, true><<<NN, 256, 0, stream>>>(
                Wg0m, Wxg0, bg0m, h0b, Ah0, h0b, h0b, x, Axf, h0f, zf, rhb, nullptr, t);
            transpose_to_bf<false><<<gT, 256, 0, stream>>>(rhb, tmpT);
            gemm_mfma<<<gG, 256, 0, stream>>>(Abf, tmpT, Arh);
            napl_mfma<2, 2, false, true><<<NN, 128, 0, stream>>>(
                Wc0m, Wxc0, bc0m, rhb, Arh, rhb, rhb, x, Axf, h0f, zf, h0b, h0f, t);
            transpose_to_bf<false><<<gT, 256, 0, stream>>>(h0b, tmpT);
            gemm_mfma<<<gG, 256, 0, stream>>>(Abf, tmpT, Ah0);
            napl_mfma<4, 4, true, false><<<NN, 256, 0, stream>>>(
                Wg1m, nullptr, bg1m, h0b, Ah0, h1b, Ah1, x, Axf, h1f, zf, rhb, nullptr, t);
            transpose_to_bf<false><<<gT, 256, 0, stream>>>(rhb, tmpT);
            gemm_mfma<<<gG, 256, 0, stream>>>(Abf, tmpT, Arh);
            napl_mfma<4, 2, false, false><<<NN, 128, 0, stream>>>(
                Wc1m, nullptr, bc1m, h0b, Ah0, rhb, Arh, x, Axf, h1f, zf, h1b, h1f, t);
            transpose_to_bf<false><<<gT, 256, 0, stream>>>(h1b, h1T);
        }
    } else {
        // ---------- Path B: round-2 LDS-rebuild NAPL (proven) ----------
        for (int t = 0; t < TT; ++t) {
            gemm_mfma<<<gG, 256, 0, stream>>>(Abf, h1T, Ah1);
            napl_kernel<1, true, true><<<dim3(NN, 2), 256, 0, stream>>>(
                node_emb, Wg0, bg0, x, Axf, h0f, Ah0, zf, rhb, t);
            transpose_to_bf<false><<<gT, 256, 0, stream>>>(rhb, tmpT);
            gemm_mfma<<<gG, 256, 0, stream>>>(Abf, tmpT, Arh);
            napl_kernel<1, true, false><<<dim3(NN, 1), 256, 0, stream>>>(
                node_emb, Wc0, bc0, x, Axf, rhb, Arh, zf, h0f, t);
            transpose_to_bf<true><<<gT, 256, 0, stream>>>(h0f, tmpT);
            gemm_mfma<<<gG, 256, 0, stream>>>(Abf, tmpT, Ah0);
            napl_kernel<HH, false, true><<<dim3(NN, 2), 256, 0, stream>>>(
                node_emb, Wg1, bg1, h0f, Ah0, h1f, Ah1, zf, rhb, t);
            transpose_to_bf<false><<<gT, 256, 0, stream>>>(rhb, tmpT);
            gemm_mfma<<<gG, 256, 0, stream>>>(Abf, tmpT, Arh);
            napl_kernel<HH, false, false><<<dim3(NN, 1), 256, 0, stream>>>(
                node_emb, Wc1, bc1, h0f, Ah0, rhb, Arh, zf, h1f, t);
            transpose_to_bf<true><<<gT, 256, 0, stream>>>(h1f, h1T);
        }
    }

    head_kernel<<<(BB * NN + 255) / 256, 256, 0, stream>>>(h1f, head_w, head_b, y);
}

// Round 5
// 10592.906 us; speedup vs baseline: 1.7006x; 1.7006x over previous
//
#include <hip/hip_runtime.h>
#include <math.h>

#define NN 2000
#define BB 32
#define TT 24
#define T_OUT 12
#define HH 64
#define DD 10
#define NP 2048   // padded node dim
#define BC 2048   // B*H columns (j = b*64 + c)

typedef unsigned short ushort_t;
typedef __bf16 bf16x8 __attribute__((ext_vector_type(8)));
typedef float f32x4 __attribute__((ext_vector_type(4)));

__device__ __forceinline__ float sigmoidf_(float x) { return 1.f / (1.f + expf(-x)); }

__device__ __forceinline__ ushort_t f2bf(float f) {
    unsigned int u = __float_as_uint(f);
    unsigned int r = (u + 0x7FFFu + ((u >> 16) & 1u)) >> 16;
    return (ushort_t)r;
}
__device__ __forceinline__ float bf2f(ushort_t s) {
    return __uint_as_float(((unsigned int)s) << 16);
}

__device__ __forceinline__ void glld16(const ushort_t* g, ushort_t* lds) {
    __builtin_amdgcn_global_load_lds(
        (const __attribute__((address_space(1))) char*)g,
        (__attribute__((address_space(3))) char*)lds, 16, 0, 0);
}

// ---------------- workspace layout (bytes), high-water 122,896,384 ----------------
constexpr size_t SZ_NPNP2 = (size_t)NP * NP * 2;   // 8,388,608
constexpr size_t SZ_ST4   = (size_t)NN * BC * 4;   // 16,384,000
constexpr size_t SZ_ST2   = (size_t)NN * BC * 2;   // 8,192,000

constexpr size_t ABF_OFF  = 0;
constexpr size_t H1T_OFF  = ABF_OFF + SZ_NPNP2;
constexpr size_t TMPT_OFF = H1T_OFF + SZ_NPNP2;
constexpr size_t H0F_OFF  = TMPT_OFF + SZ_NPNP2;
constexpr size_t H1F_OFF  = H0F_OFF + SZ_ST4;
constexpr size_t ZF_OFF   = H1F_OFF + SZ_ST4;       // f32; overlaid with A_f32 in setup
constexpr size_t H0B_OFF  = ZF_OFF + SZ_ST4;
constexpr size_t H1B_OFF  = H0B_OFF + SZ_ST2;
constexpr size_t RHB_OFF  = H1B_OFF + SZ_ST2;
constexpr size_t AH0_OFF  = RHB_OFF + SZ_ST2;
constexpr size_t AHX_OFF  = AH0_OFF + SZ_ST2;       // shared: Arh0 / Ah1 / Arh1
constexpr size_t AXF_OFF  = AHX_OFF + SZ_ST2;       // [B][T][N] f32
constexpr size_t BTG0_OFF = AXF_OFF + (size_t)BB * TT * NN * 4;
constexpr size_t BTC0_OFF = BTG0_OFF + (size_t)DD * 128 * 128 * 2;  // 327,680
constexpr size_t BTG1_OFF = BTC0_OFF + (size_t)DD * 64 * 128 * 2;   // 163,840
constexpr size_t BTC1_OFF = BTG1_OFF + (size_t)DD * 128 * 256 * 2;  // 655,360
constexpr size_t WS_TOP   = BTC1_OFF + (size_t)DD * 64 * 256 * 2;   // 122,896,384

// ---------------- A_f32 = row_softmax(relu(E E^T)) ----------------
__global__ __launch_bounds__(256) void compute_A_kernel(const float* __restrict__ E,
                                                        float* __restrict__ A) {
    const int row = blockIdx.x;
    const int tid = threadIdx.x;
    float er[DD];
#pragma unroll
    for (int d = 0; d < DD; ++d) er[d] = E[row * DD + d];
    __shared__ float red[8];

    float lmax = -1e30f;
    for (int c = tid; c < NN; c += 256) {
        float s = 0.f;
#pragma unroll
        for (int d = 0; d < DD; ++d) s += er[d] * E[c * DD + d];
        s = fmaxf(s, 0.f);
        A[(size_t)row * NN + c] = s;
        lmax = fmaxf(lmax, s);
    }
#pragma unroll
    for (int o = 32; o > 0; o >>= 1) lmax = fmaxf(lmax, __shfl_down(lmax, o, 64));
    if ((tid & 63) == 0) red[tid >> 6] = lmax;
    __syncthreads();
    const float rmax = fmaxf(fmaxf(red[0], red[1]), fmaxf(red[2], red[3]));
    __syncthreads();

    float lsum = 0.f;
    for (int c = tid; c < NN; c += 256) {
        float v = expf(A[(size_t)row * NN + c] - rmax);
        A[(size_t)row * NN + c] = v;
        lsum += v;
    }
#pragma unroll
    for (int o = 32; o > 0; o >>= 1) lsum += __shfl_down(lsum, o, 64);
    if ((tid & 63) == 0) red[4 + (tid >> 6)] = lsum;
    __syncthreads();
    const float inv = 1.f / (red[4] + red[5] + red[6] + red[7]);
    for (int c = tid; c < NN; c += 256) A[(size_t)row * NN + c] *= inv;
}

// ---------------- A_f32 -> A_bf [2048][2048] with zero pad ----------------
__global__ __launch_bounds__(256) void convert_A(const float* __restrict__ Af,
                                                 ushort_t* __restrict__ Ab) {
    size_t idx = (size_t)blockIdx.x * 256 + threadIdx.x;
    int r = (int)(idx >> 11), c = (int)(idx & 2047);
    float v = (r < NN && c < NN) ? Af[(size_t)r * NN + c] : 0.f;
    Ab[idx] = f2bf(v);
}

// ---------------- Ax[b,t,n] = sum_m A[n,m] x[b,t,m]  (f32, one-time) ----------------
__global__ __launch_bounds__(256) void ax_kernel(const float* __restrict__ A,
                                                 const float* __restrict__ x,
                                                 float* __restrict__ Ax) {
    __shared__ float As[64][65];
    __shared__ float xs[64][25];
    const int n0 = blockIdx.x * 64;
    const int b = blockIdx.y;
    const int tid = threadIdx.x;
    float acc[6] = {0, 0, 0, 0, 0, 0};
    for (int m0 = 0; m0 < NN; m0 += 64) {
#pragma unroll
        for (int l = 0; l < 16; ++l) {
            int idx = tid + l * 256;
            int r = idx >> 6, c = idx & 63;
            int n = n0 + r, m = m0 + c;
            As[r][c] = (n < NN && m < NN) ? A[(size_t)n * NN + m] : 0.f;
        }
        for (int idx = tid; idx < 64 * TT; idx += 256) {
            int c = idx >> 6, r = idx & 63;
            int m = m0 + r;
            xs[r][c] = (m < NN) ? x[((size_t)b * TT + c) * NN + m] : 0.f;
        }
        __syncthreads();
#pragma unroll 4
        for (int mm = 0; mm < 64; ++mm) {
#pragma unroll
            for (int j = 0; j < 6; ++j) {
                int oi = tid + j * 256;
                int r = oi / TT, c = oi % TT;
                acc[j] += As[r][mm] * xs[mm][c];
            }
        }
        __syncthreads();
    }
#pragma unroll
    for (int j = 0; j < 6; ++j) {
        int oi = tid + j * 256;
        int r = oi / TT, c = oi % TT;
        int n = n0 + r;
        if (n < NN) Ax[((size_t)b * TT + c) * NN + n] = acc[j];
    }
}

// ---------------- transpose bf16 [n][j] -> [j][n], zero-fill n>=NN ----------------
__global__ __launch_bounds__(256) void transpose_bf(const ushort_t* __restrict__ src,
                                                    ushort_t* __restrict__ dst) {
    __shared__ ushort_t tile[64][65];
    const int jb = blockIdx.x * 64, nb = blockIdx.y * 64;
    const int tid = threadIdx.x;
#pragma unroll
    for (int l = 0; l < 16; ++l) {
        int idx = tid + l * 256;
        int r = idx >> 6, c = idx & 63;  // r: n-local, c: j-local
        int n = nb + r;
        tile[r][c] = (n < NN) ? src[(size_t)n * BC + jb + c] : (ushort_t)0;
    }
    __syncthreads();
#pragma unroll
    for (int l = 0; l < 16; ++l) {
        int idx = tid + l * 256;
        int r = idx >> 6, c = idx & 63;  // r: j-local, c: n-local
        dst[(size_t)(jb + r) * NP + nb + c] = tile[c][r];
    }
}

// ---------------- MFMA GEMM: Y[n][j] = sum_m A[n][m] * XT[j][m], bf16 ----------------
// 64x128 tile, BK=32, 4 waves (col-split), grid (32,16)=512 blocks (2/CU).
__global__ __launch_bounds__(256) void gemm_mfma(const ushort_t* __restrict__ Ab,
                                                 const ushort_t* __restrict__ XT,
                                                 ushort_t* __restrict__ Y) {
    __shared__ __align__(16) ushort_t As[64 * 32];
    __shared__ __align__(16) ushort_t Bs[128 * 32];
    const int tid = threadIdx.x;
    const int w = tid >> 6, l = tid & 63, lr = l & 15, lg = l >> 4;
    const int n0 = blockIdx.x * 64, j0 = blockIdx.y * 128;
    f32x4 acc[4][2] = {};

    for (int ks = 0; ks < NP / 32; ++ks) {
        const int k0 = ks * 32;
        {   // A tile: 64 rows x 32 k, 1 issue, source pre-swizzled (inverse of read XOR)
            const int row = tid >> 2, c16 = tid & 3;
            glld16(Ab + (size_t)(n0 + row) * NP + k0 + ((c16 ^ (row & 3)) << 3),
                   (ushort_t*)((char*)As + tid * 16));
        }
#pragma unroll
        for (int p = 0; p < 2; ++p) {  // B tile: 128 rows x 32 k, 2 issues
            const int idx = p * 256 + tid;
            const int row = idx >> 2, c16 = idx & 3;
            glld16(XT + (size_t)(j0 + row) * NP + k0 + ((c16 ^ (row & 3)) << 3),
                   (ushort_t*)((char*)Bs + idx * 16));
        }
        __syncthreads();

        bf16x8 av[4], bv[2];
#pragma unroll
        for (int m = 0; m < 4; ++m) {
            const int rr = m * 16 + lr;
            av[m] = *(const bf16x8*)&As[rr * 32 + ((lg * 8) ^ ((rr & 3) << 3))];
        }
#pragma unroll
        for (int nt = 0; nt < 2; ++nt) {
            const int br = w * 32 + nt * 16 + lr;
            bv[nt] = *(const bf16x8*)&Bs[br * 32 + ((lg * 8) ^ ((br & 3) << 3))];
        }
#pragma unroll
        for (int m = 0; m < 4; ++m)
#pragma unroll
            for (int nt = 0; nt < 2; ++nt)
                acc[m][nt] = __builtin_amdgcn_mfma_f32_16x16x32_bf16(av[m], bv[nt], acc[m][nt], 0, 0, 0);
        __syncthreads();
    }

#pragma unroll
    for (int m = 0; m < 4; ++m)
#pragma unroll
        for (int r = 0; r < 4; ++r) {
            const int n = n0 + m * 16 + lg * 4 + r;
            if (n < NN) {
#pragma unroll
                for (int nt = 0; nt < 2; ++nt)
                    Y[(size_t)n * BC + j0 + w * 32 + nt * 16 + lr] = f2bf(acc[m][nt][r]);
            }
        }
}

// ---------------- prep: Bt[d][o][K] bf16 from pool (B^T form for MFMA) ----------------
// L0: K=128, k -> (kk=k>>6, i=1+(k&63)).  L1: K=256, s=k>>6 -> (kk=s&1, i=(s>>1)*64+(k&63)).
template <int CI, int CO, bool L0>
__global__ __launch_bounds__(256) void prepW(const float* __restrict__ Wp,
                                             ushort_t* __restrict__ Bt) {
    constexpr int K = L0 ? 128 : 256;
    const int idx = blockIdx.x * 256 + threadIdx.x;
    if (idx >= DD * CO * K) return;
    const int d = idx / (CO * K);
    const int rem = idx - d * CO * K;
    const int o = rem / K;
    const int k = rem - o * K;
    const int s = k >> 6, c = k & 63;
    const int kk = L0 ? s : (s & 1);
    const int i = L0 ? (1 + c) : ((s >> 1) * 64 + c);
    Bt[idx] = f2bf(Wp[((size_t)(d * 2 + kk) * CI + i) * CO + o]);
}

// ---------------- factored-MFMA NAPL gconv ----------------
// Block = 64 output rows j (= 2 nodes x 32 batches). out[j,o] = sum_d e[n,d]*(in @ Wp[d])[j,o].
// Input segs staged once in LDS (XOR-swizzled); B-frags stream from tiny Bt pools (L2).
// GATE (CO=128): o<64 -> z=sigma -> zf ; o>=64 -> rh = sigma*hf -> outb.
// CAND (CO=64): h_new = z*hf + (1-z)*tanh(val) -> outf (f32) + outb (bf16).
template <int NSEGS, int CO, bool GATE, bool HASX>
__global__ __launch_bounds__(256) void napl2(
    const ushort_t* __restrict__ Bt, const float* __restrict__ bp,
    const float* __restrict__ emb, const float* __restrict__ WxPool,
    const ushort_t* __restrict__ s0p, const ushort_t* __restrict__ s1p,
    const ushort_t* __restrict__ s2p, const ushort_t* __restrict__ s3p,
    const float* __restrict__ xv, const float* __restrict__ axv,
    const float* hf, float* __restrict__ zf,
    ushort_t* __restrict__ outb, float* outf, int t) {
    constexpr int K = NSEGS * 64;
    constexpr int NT = (CO == 128) ? 2 : 1;
    __shared__ __align__(16) ushort_t As[NSEGS * 64 * 64];
    const int tid = threadIdx.x;
    const int w = tid >> 6, l = tid & 63, lr = l & 15, lg = l >> 4;
    const int n0 = blockIdx.x * 2;
    const int ob = w * (16 * NT);
    const ushort_t* segs[4] = {s0p, s1p, s2p, s3p};

    // stage A: seg-major [s][64 rows][64 cols], source pre-swizzled by ((row&7)<<3) els
#pragma unroll
    for (int s = 0; s < NSEGS; ++s) {
        const ushort_t* sp = segs[s];
#pragma unroll
        for (int p = 0; p < 2; ++p) {
            const int idx = p * 256 + tid;
            const int row = idx >> 3, c16 = idx & 7;
            glld16(sp + (size_t)(n0 + (row >> 5)) * BC + (row & 31) * 64 +
                       ((c16 ^ (row & 7)) << 3),
                   (ushort_t*)((char*)As + s * 8192 + idx * 16));
        }
    }
    __syncthreads();

    f32x4 OUT[4][NT] = {};
#pragma unroll 1
    for (int d = 0; d < DD; ++d) {
        const ushort_t* btd = Bt + (size_t)d * CO * K;
        const float ea = emb[n0 * DD + d];
        const float eb = emb[(n0 + 1) * DD + d];
        f32x4 P[4][NT] = {};
#pragma unroll
        for (int s = 0; s < NSEGS; ++s)
#pragma unroll
            for (int h2 = 0; h2 < 2; ++h2) {
                const int kin = h2 * 32 + lg * 8;
                const int kg = s * 64 + kin;
                bf16x8 bv[NT];
#pragma unroll
                for (int nt = 0; nt < NT; ++nt)
                    bv[nt] = *(const bf16x8*)&btd[(size_t)(ob + nt * 16 + lr) * K + kg];
                bf16x8 av[4];
#pragma unroll
                for (int m = 0; m < 4; ++m) {
                    const int rr = m * 16 + lr;
                    av[m] = *(const bf16x8*)&As[s * 4096 + rr * 64 + (kin ^ ((rr & 7) << 3))];
                }
#pragma unroll
                for (int m = 0; m < 4; ++m)
#pragma unroll
                    for (int nt = 0; nt < NT; ++nt)
                        P[m][nt] = __builtin_amdgcn_mfma_f32_16x16x32_bf16(av[m], bv[nt], P[m][nt], 0, 0, 0);
            }
#pragma unroll
        for (int m = 0; m < 4; ++m) {
            const float e = (m < 2) ? ea : eb;
#pragma unroll
            for (int nt = 0; nt < NT; ++nt)
#pragma unroll
                for (int r = 0; r < 4; ++r)
                    OUT[m][nt][r] += e * P[m][nt][r];
        }
    }

    // per-node bias and (optional) x rank-2 weights
    float bias[2][NT];
#pragma unroll
    for (int nd = 0; nd < 2; ++nd)
#pragma unroll
        for (int nt = 0; nt < NT; ++nt) {
            float s_ = 0.f;
#pragma unroll
            for (int d = 0; d < DD; ++d)
                s_ += emb[(n0 + nd) * DD + d] * bp[d * CO + ob + nt * 16 + lr];
            bias[nd][nt] = s_;
        }
    float wx[2][2][NT] = {};
    if (HASX) {
#pragma unroll
        for (int kk = 0; kk < 2; ++kk)
#pragma unroll
            for (int nd = 0; nd < 2; ++nd)
#pragma unroll
                for (int nt = 0; nt < NT; ++nt) {
                    float s_ = 0.f;
#pragma unroll
                    for (int d = 0; d < DD; ++d)
                        s_ += emb[(n0 + nd) * DD + d] *
                              WxPool[(size_t)(d * 2 + kk) * 65 * CO + ob + nt * 16 + lr];
                    wx[kk][nd][nt] = s_;
                }
    }

#pragma unroll
    for (int m = 0; m < 4; ++m) {
        const int nd = m >> 1;
        const int n = n0 + nd;
#pragma unroll
        for (int r = 0; r < 4; ++r) {
            const int row = m * 16 + lg * 4 + r;
            const int b = row & 31;
            const size_t nb = (size_t)n * BC + b * 64;
            float xt = 0.f, axt = 0.f;
            if (HASX) {
                xt = xv[((size_t)b * TT + t) * NN + n];
                axt = axv[((size_t)b * TT + t) * NN + n];
            }
#pragma unroll
            for (int nt = 0; nt < NT; ++nt) {
                const int o = ob + nt * 16 + lr;
                float val = OUT[m][nt][r] + bias[nd][nt];
                if (HASX) val += xt * wx[0][nd][nt] + axt * wx[1][nd][nt];
                if (GATE) {
                    const float sg = sigmoidf_(val);
                    if (ob < 64) {
                        zf[nb + o] = sg;
                    } else {
                        outb[nb + (o - 64)] = f2bf(sg * hf[nb + (o - 64)]);
                    }
                } else {
                    const float hc = tanhf(val);
                    const float z = zf[nb + o];
                    const float hn = z * hf[nb + o] + (1.f - z) * hc;
                    outf[nb + o] = hn;
                    outb[nb + o] = f2bf(hn);
                }
            }
        }
    }
}

// ---------------- head: y[b,ot,n] = hb[ot] + sum_h h1[n][b*64+h]*hw[ot,h] ----------------
__global__ __launch_bounds__(256) void head_kernel(const float* __restrict__ h1,
                                                   const float* __restrict__ hw,
                                                   const float* __restrict__ hb,
                                                   float* __restrict__ y) {
    __shared__ float wl[T_OUT * HH];
    const int tid = threadIdx.x;
    for (int idx = tid; idx < T_OUT * HH; idx += 256) wl[idx] = hw[idx];
    __syncthreads();
    const int gi = blockIdx.x * 256 + tid;
    if (gi >= BB * NN) return;
    const int b = gi / NN, n = gi % NN;
    float acc[T_OUT];
#pragma unroll
    for (int ot = 0; ot < T_OUT; ++ot) acc[ot] = hb[ot];
    for (int h = 0; h < HH; ++h) {
        float v = h1[(size_t)n * BC + b * 64 + h];
#pragma unroll
        for (int ot = 0; ot < T_OUT; ++ot) acc[ot] += v * wl[ot * HH + h];
    }
#pragma unroll
    for (int ot = 0; ot < T_OUT; ++ot)
        y[((size_t)b * T_OUT + ot) * NN + n] = acc[ot];
}

extern "C" void kernel_launch(void* const* d_in, const int* in_sizes, int n_in,
                              void* d_out, int out_size, void* d_ws, size_t ws_size,
                              hipStream_t stream) {
    const float* x = (const float*)d_in[0];
    const float* node_emb = (const float*)d_in[1];
    const float* adapt_emb = (const float*)d_in[2];
    const float* Wg0 = (const float*)d_in[3];
    const float* bg0 = (const float*)d_in[4];
    const float* Wc0 = (const float*)d_in[5];
    const float* bc0 = (const float*)d_in[6];
    const float* Wg1 = (const float*)d_in[7];
    const float* bg1 = (const float*)d_in[8];
    const float* Wc1 = (const float*)d_in[9];
    const float* bc1 = (const float*)d_in[10];
    const float* head_w = (const float*)d_in[11];
    const float* head_b = (const float*)d_in[12];
    float* y = (float*)d_out;

    char* ws = (char*)d_ws;
    ushort_t* Abf  = (ushort_t*)(ws + ABF_OFF);
    ushort_t* h1T  = (ushort_t*)(ws + H1T_OFF);
    ushort_t* tmpT = (ushort_t*)(ws + TMPT_OFF);
    float* h0f = (float*)(ws + H0F_OFF);
    float* h1f = (float*)(ws + H1F_OFF);
    float* zf  = (float*)(ws + ZF_OFF);
    ushort_t* h0b = (ushort_t*)(ws + H0B_OFF);
    ushort_t* h1b = (ushort_t*)(ws + H1B_OFF);
    ushort_t* rhb = (ushort_t*)(ws + RHB_OFF);
    ushort_t* Ah0 = (ushort_t*)(ws + AH0_OFF);
    ushort_t* AhX = (ushort_t*)(ws + AHX_OFF);
    float* Axf = (float*)(ws + AXF_OFF);
    ushort_t* Btg0 = (ushort_t*)(ws + BTG0_OFF);
    ushort_t* Btc0 = (ushort_t*)(ws + BTC0_OFF);
    ushort_t* Btg1 = (ushort_t*)(ws + BTG1_OFF);
    ushort_t* Btc1 = (ushort_t*)(ws + BTC1_OFF);
    float* Af32 = zf;  // overlay: consumed before first gate writes z

    hipMemsetAsync(h0f, 0, SZ_ST4, stream);
    hipMemsetAsync(h1f, 0, SZ_ST4, stream);
    hipMemsetAsync(h0b, 0, SZ_ST2, stream);
    hipMemsetAsync(h1b, 0, SZ_ST2, stream);
    hipMemsetAsync(Ah0, 0, SZ_ST2, stream);
    hipMemsetAsync(h1T, 0, SZ_NPNP2, stream);

    // one-time setup
    compute_A_kernel<<<NN, 256, 0, stream>>>(adapt_emb, Af32);
    ax_kernel<<<dim3((NN + 63) / 64, BB), 256, 0, stream>>>(Af32, x, Axf);
    convert_A<<<(NP * NP) / 256, 256, 0, stream>>>(Af32, Abf);
    prepW<65, 128, true><<<(DD * 128 * 128 + 255) / 256, 256, 0, stream>>>(Wg0, Btg0);
    prepW<65, 64, true><<<(DD * 64 * 128 + 255) / 256, 256, 0, stream>>>(Wc0, Btc0);
    prepW<128, 128, false><<<(DD * 128 * 256 + 255) / 256, 256, 0, stream>>>(Wg1, Btg1);
    prepW<128, 64, false><<<(DD * 64 * 256 + 255) / 256, 256, 0, stream>>>(Wc1, Btc1);

    const dim3 gG(NP / 64, NP / 128);  // 32 x 16 = 512 blocks
    const dim3 gT(NP / 64, NP / 64);   // 32 x 32
    const int gN = NN * BB / 64;       // 1000 blocks

    for (int t = 0; t < TT; ++t) {
        // layer0 gate: segs [h0 | A h0] (+x rank-2) -> zf, rhb
        napl2<2, 128, true, true><<<gN, 256, 0, stream>>>(
            Btg0, bg0, node_emb, Wg0, h0b, Ah0, h0b, h0b, x, Axf, h0f, zf, rhb, nullptr, t);
        transpose_bf<<<gT, 256, 0, stream>>>(rhb, tmpT);
        gemm_mfma<<<gG, 256, 0, stream>>>(Abf, tmpT, AhX);  // Arh0
        // layer0 cand: segs [rh | A rh] (+x) -> h0f, h0b
        napl2<2, 64, false, true><<<gN, 256, 0, stream>>>(
            Btc0, bc0, node_emb, Wc0, rhb, AhX, rhb, rhb, x, Axf, h0f, zf, h0b, h0f, t);
        transpose_bf<<<gT, 256, 0, stream>>>(h0b, tmpT);
        gemm_mfma<<<gG, 256, 0, stream>>>(Abf, tmpT, Ah0);  // A h0_new (also next step's gate0)
        gemm_mfma<<<gG, 256, 0, stream>>>(Abf, h1T, AhX);   // A h1_prev
        // layer1 gate: segs [h0new | A h0new | h1 | A h1] -> zf, rhb
        napl2<4, 128, true, false><<<gN, 256, 0, stream>>>(
            Btg1, bg1, node_emb, nullptr, h0b, Ah0, h1b, AhX, nullptr, nullptr, h1f, zf, rhb, nullptr, t);
        transpose_bf<<<gT, 256, 0, stream>>>(rhb, tmpT);
        gemm_mfma<<<gG, 256, 0, stream>>>(Abf, tmpT, AhX);  // Arh1
        // layer1 cand: segs [h0new | A h0new | rh1 | A rh1] -> h1f, h1b
        napl2<4, 64, false, false><<<gN, 256, 0, stream>>>(
            Btc1, bc1, node_emb, nullptr, h0b, Ah0, rhb, AhX, nullptr, nullptr, h1f, zf, h1b, h1f, t);
        transpose_bf<<<gT, 256, 0, stream>>>(h1b, h1T);
    }

    head_kernel<<<(BB * NN + 255) / 256, 256, 0, stream>>>(h1f, head_w, head_b, y);
}